// Round 8
// baseline (51.179 us; speedup 1.0000x reference)
//
#include <hip/hip_runtime.h>
#include <math.h>

// out[b,i,h,w] = Ar[b,h,i]*cos(2*pi*i*w/128)/128 - Ai[b,h,i]*sin(2*pi*i*w/128)/128
// A = row-DFT of x (fft2 + ifft over H == fft over W). mask unused.
// x real => out[b,128-i] == out[b,i] EXACTLY: compute i=0..64, store mirrors.
//
// v7: v6 (zero LDS / zero barriers / register x / sequential plane streams)
// + UNIFORM COMPUTE SPREAD: the next plane's DFT is interleaved into the
// store loop (1 sample per chain between consecutive stores) so waves never
// pause stores for a ~700-cycle DFT lump (anti-convoy). i=0 (row mean) and
// i=64 (alternating sum) peeled as trivial cases.
// Grid: 1056 = 32 b x 33 groups. g<32: planes {2g,2g+1}+mirrors; g=32: {64}.

typedef float f32x4 __attribute__((ext_vector_type(4)));

__device__ __forceinline__ void rot_step(float& cr, float& ci, float dc, float ds) {
    const float ncr = fmaf(cr, dc, -ci * ds);
    ci = fmaf(cr, ds, ci * dc);
    cr = ncr;
}

__device__ __forceinline__ void dft_full(const float* xs, int i, int half,
                                         float& arO, float& aiO) {
    float ss, cs;
    sincospif((float)i * (1.0f / 64.0f), &ss, &cs);
    const float dc = cs, ds = -ss;
    float ar = 0.0f, ai = 0.0f;
#pragma unroll
    for (int ch = 0; ch < 2; ++ch) {
        const int u0 = half * 64 + ch * 32;
        float s0, c0;
        sincospif((float)((i * u0) & 127) * (1.0f / 64.0f), &s0, &c0);
        float cr = c0, ci = -s0;
#pragma unroll
        for (int j = 0; j < 32; ++j) {
            const float xv = xs[ch * 32 + j];
            ar = fmaf(xv, cr, ar);
            ai = fmaf(xv, ci, ai);
            rot_step(cr, ci, dc, ds);
        }
    }
    ar += __shfl_xor(ar, 1);
    ai += __shfl_xor(ai, 1);
    arO = ar * (1.0f / 128.0f);
    aiO = ai * (1.0f / 128.0f);
}

__device__ __forceinline__ void store_iter(f32x4* __restrict__ o, int j, int lane, int wv,
                                           float arC, float aiC,
                                           const float (&cwv)[4], const float (&swv)[4]) {
    // wave wv writes f32x4 q = wv*1024 + 64j + lane (1KB/instr, coalesced);
    // row hh = 32wv + 2j + (lane>>5); A owner lane = 4j + 2*(lane>>5).
    const int src = 4 * j + 2 * (lane >> 5);
    const float a  = __shfl(arC, src);
    const float bb = __shfl(aiC, src);
    f32x4 v;
    v.x = fmaf(a, cwv[0], -bb * swv[0]);
    v.y = fmaf(a, cwv[1], -bb * swv[1]);
    v.z = fmaf(a, cwv[2], -bb * swv[2]);
    v.w = fmaf(a, cwv[3], -bb * swv[3]);
    o[wv * 1024 + j * 64 + lane] = v;
}

__global__ __launch_bounds__(256) void kspace_v7(const float* __restrict__ x,
                                                 float* __restrict__ out) {
    const int blk  = blockIdx.x;       // 0..1055
    const int b    = blk / 33;
    const int g    = blk % 33;
    const int t    = threadIdx.x;
    const int wv   = t >> 6;
    const int lane = t & 63;
    const int h    = wv * 32 + (lane >> 1);
    const int half = lane & 1;

    // ---- my half-row (64 floats, 256 B contiguous) into registers ----
    const float* xp = x + ((size_t)b * 128 + h) * 128 + half * 64;
    float xs[64];
#pragma unroll
    for (int j = 0; j < 16; ++j) {
        const f32x4 v = ((const f32x4*)xp)[j];
        xs[4 * j + 0] = v.x;
        xs[4 * j + 1] = v.y;
        xs[4 * j + 2] = v.z;
        xs[4 * j + 3] = v.w;
    }

    f32x4* const out4 = (f32x4*)out + (size_t)b * 128 * 4096;

    if (g == 32) {
        // plane 64: A = sum (-1)^u x / 128 (real); cos(pi*w)=(-1)^w, sin=0
        float ar = 0.0f;
#pragma unroll
        for (int j = 0; j < 64; ++j) ar += (j & 1) ? -xs[j] : xs[j];
        ar += __shfl_xor(ar, 1);
        ar *= (1.0f / 128.0f);
        f32x4* const o = out4 + (size_t)64 * 4096;
#pragma unroll
        for (int j = 0; j < 16; ++j) {
            const int src = 4 * j + 2 * (lane >> 5);
            const float a = __shfl(ar, src);
            f32x4 v;
            v.x = a; v.y = -a; v.z = a; v.w = -a;
            o[wv * 1024 + j * 64 + lane] = v;
        }
        return;
    }

    const int i0 = 2 * g, i1 = 2 * g + 1;

    // ---- DFT of first plane (exposed once; i0=0 is a trivial mean) ----
    float arC, aiC;
    if (g == 0) {
        float s = 0.0f;
#pragma unroll
        for (int j = 0; j < 64; ++j) s += xs[j];
        s += __shfl_xor(s, 1);
        arC = s * (1.0f / 128.0f);
        aiC = 0.0f;
    } else {
        dft_full(xs, i0, half, arC, aiC);
    }

    // ---- init pipelined DFT state for plane i1 ----
    float dc, ds, cr0, ci0, cr1, ci1;
    float arN = 0.0f, aiN = 0.0f;
    {
        float ss, cs;
        sincospif((float)i1 * (1.0f / 64.0f), &ss, &cs);
        dc = cs; ds = -ss;
        float s0, c0;
        sincospif((float)((i1 * (half * 64)) & 127) * (1.0f / 64.0f), &s0, &c0);
        cr0 = c0; ci0 = -s0;
        float s1, c1;
        sincospif((float)((i1 * (half * 64 + 32)) & 127) * (1.0f / 64.0f), &s1, &c1);
        cr1 = c1; ci1 = -s1;
    }

    // ---- per-lane trig for plane i0's 4 w-columns ----
    const int wbase = (lane & 31) * 4;
    float cwv[4], swv[4];
#pragma unroll
    for (int c = 0; c < 4; ++c) {
        const int k = (i0 * (wbase + c)) & 127;
        sincospif((float)k * (1.0f / 64.0f), &swv[c], &cwv[c]);
    }

    // ---- plane i0 stores with i1's DFT spread between stores ----
    if (g == 0) {
        // i0=0: single pass (no distinct mirror), 2 DFT samples/chain per iter
        f32x4* const o = out4;   // plane 0
#pragma unroll
        for (int j = 0; j < 16; ++j) {
            store_iter(o, j, lane, wv, arC, aiC, cwv, swv);
#pragma unroll
            for (int s = 0; s < 2; ++s) {
                const int n = 2 * j + s;
                const float x0 = xs[n], x1 = xs[32 + n];
                arN = fmaf(x0, cr0, arN); aiN = fmaf(x0, ci0, aiN);
                arN = fmaf(x1, cr1, arN); aiN = fmaf(x1, ci1, aiN);
                rot_step(cr0, ci0, dc, ds);
                rot_step(cr1, ci1, dc, ds);
            }
        }
    } else {
#pragma unroll
        for (int pass = 0; pass < 2; ++pass) {
            f32x4* const o = out4 + (size_t)(pass ? (128 - i0) : i0) * 4096;
#pragma unroll
            for (int j = 0; j < 16; ++j) {
                store_iter(o, j, lane, wv, arC, aiC, cwv, swv);
                const int n = pass * 16 + j;          // compile-time (pass unrolled)
                const float x0 = xs[n], x1 = xs[32 + n];
                arN = fmaf(x0, cr0, arN); aiN = fmaf(x0, ci0, aiN);
                arN = fmaf(x1, cr1, arN); aiN = fmaf(x1, ci1, aiN);
                rot_step(cr0, ci0, dc, ds);
                rot_step(cr1, ci1, dc, ds);
            }
        }
    }

    // ---- finish i1's DFT, then store plane i1 + mirror ----
    arN += __shfl_xor(arN, 1);
    aiN += __shfl_xor(aiN, 1);
    arC = arN * (1.0f / 128.0f);
    aiC = aiN * (1.0f / 128.0f);
#pragma unroll
    for (int c = 0; c < 4; ++c) {
        const int k = (i1 * (wbase + c)) & 127;
        sincospif((float)k * (1.0f / 64.0f), &swv[c], &cwv[c]);
    }
#pragma unroll
    for (int pass = 0; pass < 2; ++pass) {
        f32x4* const o = out4 + (size_t)(pass ? (128 - i1) : i1) * 4096;
#pragma unroll
        for (int j = 0; j < 16; ++j) {
            store_iter(o, j, lane, wv, arC, aiC, cwv, swv);
        }
    }
}

extern "C" void kernel_launch(void* const* d_in, const int* in_sizes, int n_in,
                              void* d_out, int out_size, void* d_ws, size_t ws_size,
                              hipStream_t stream) {
    const float* x = (const float*)d_in[0];   // (32,1,128,128) f32; mask unused
    float* out = (float*)d_out;               // (32,128,128,128) f32
    kspace_v7<<<dim3(1056), dim3(256), 0, stream>>>(x, out);
}